// Round 1
// baseline (137.889 us; speedup 1.0000x reference)
//
#include <hip/hip_runtime.h>
#include <hip/hip_bf16.h>

typedef unsigned short u16;
typedef unsigned int u32;
typedef __attribute__((ext_vector_type(8))) short bf16x8;
typedef __attribute__((ext_vector_type(4))) float floatx4;
typedef __attribute__((ext_vector_type(2))) float f32x2;

__device__ __forceinline__ float bflo(u32 u){ union{u32 i; float f;}v; v.i=u<<16; return v.f; }
__device__ __forceinline__ float bfhi(u32 u){ union{u32 i; float f;}v; v.i=u&0xFFFF0000u; return v.f; }
__device__ __forceinline__ u16 f2bf(float f){
    union{float f;u32 i;}v; v.f=f; u32 r=v.i+0x7FFFu+((v.i>>16)&1u); return (u16)(r>>16);
}
__device__ __forceinline__ u32 pkbf(float a, float b){
    union { __hip_bfloat162 h; u32 u; } cv;
    cv.h = __float22bfloat162_rn(float2{a, b});
    return cv.u;
}

#define DD 512
#define NTOK 128

// ---------------------------------------------------------------------------
// prep_t: LDS-free transpose+convert.
//   blocks 0..127 : W1 rows 0..1023 (fp32 [1024][512]) -> W1T bf16 [512 c][1024 k]
//   blocks 128..159: W2 (fp32 [512][256])             -> W2T bf16 [256 c][512 k]
// Coalesced 256B fp32 reads (8 per thread), packed cvt, one dwordx4 store.
// ---------------------------------------------------------------------------
__global__ __launch_bounds__(512) void prep_t(
    const float* __restrict__ W1, const float* __restrict__ W2,
    u16* __restrict__ W1T, u16* __restrict__ W2T)
{
    const int bid = blockIdx.x;
    const float* src; u16* dst; int sstride, dstride, kt, ct;
    if (bid < 128) { kt = bid >> 3; ct = bid & 7;  src = W1; sstride = 512; dst = W1T; dstride = 1024; }
    else { int t = bid - 128; kt = t >> 2; ct = t & 3; src = W2; sstride = 256; dst = W2T; dstride = 512; }
    const int cl = threadIdx.x & 63;               // column within 64-wide c-tile
    const int kchunk = (threadIdx.x >> 6) << 3;    // 8-k chunk per wave
    const int srow = kt * 64 + kchunk, scol = ct * 64 + cl;
    float v[8];
#pragma unroll
    for (int i = 0; i < 8; ++i) v[i] = src[(size_t)(srow + i) * sstride + scol];
    uint4 o = make_uint4(pkbf(v[0], v[1]), pkbf(v[2], v[3]),
                         pkbf(v[4], v[5]), pkbf(v[6], v[7]));
    *(uint4*)(dst + (size_t)scol * dstride + srow) = o;
}

// ---------------------------------------------------------------------------
// prep_g: Hf = features @ [W1a|W1b] as one [1024 x 1024] bf16 GEMM, K=512.
// grid (16 bM, 16 bN), 512 thr, 8 waves (4x2). 64x64 tile per block.
// A-stage: fp32->bf16 in-register, swizzled b128 store (R5-proven pattern).
// B-stage: ONE global_load_lds width-16 per wave per kc from pre-swizzled
//          W1T source (same mapping proven in fused_main's B-DMA).
// bN<8 -> Hf1b (+b1 folded), bN>=8 -> Hf2.
// ---------------------------------------------------------------------------
__global__ __launch_bounds__(512) void prep_g(
    const float* __restrict__ features, const u16* __restrict__ W1T,
    const float* __restrict__ b1, u16* __restrict__ Hf1b, u16* __restrict__ Hf2)
{
    const int bM = blockIdx.x, bN = blockIdx.y;
    const int tid = threadIdx.x;
    const int wid = tid >> 6, lane = tid & 63, lrow = lane & 15, quad = lane >> 4;
    const int wm = wid >> 1, wn = wid & 1;
    __shared__ __align__(16) u16 At[64 * 64];
    __shared__ __align__(16) u16 Btl[64 * 64];

    floatx4 acc[2];
    acc[0] = (floatx4)(0.0f); acc[1] = (floatx4)(0.0f);

    const int m = tid >> 3, seg = tid & 7, sw = m & 7;
    // B-DMA lane source: wave wid covers rows wid*8..wid*8+7 (row = output col),
    // lane>>3 = row-in-slot, lane&7 = dest 16B chunk; source chunk = dest^row&7
    // so the LDS (linear dest) ends up XOR-swizzled exactly like the old Btl.
    const int zoff = (bN >> 3) * 512;
    const u16* bsrc_lane = W1T
        + (size_t)((bN & 7) * 64 + wid * 8 + (lane >> 3)) * 1024
        + zoff + (((lane & 7) ^ (lane >> 3)) << 3);

    for (int kc = 0; kc < 8; ++kc) {
        const int k0 = kc * 64;
        __builtin_amdgcn_global_load_lds(
            (const __attribute__((address_space(1))) u32*)(bsrc_lane + k0),
            (__attribute__((address_space(3))) u32*)(Btl + wid * 512), 16, 0, 0);
        {   // stage A: 8 fp32 -> 8 bf16, one uint4, XOR-swizzled
            const float4* srcp = (const float4*)(features + (size_t)(bM * 64 + m) * DD + k0 + seg * 8);
            float4 f0 = srcp[0], f1 = srcp[1];
            *(uint4*)(At + m * 64 + ((seg ^ sw) << 3)) =
                make_uint4(pkbf(f0.x, f0.y), pkbf(f0.z, f0.w), pkbf(f1.x, f1.y), pkbf(f1.z, f1.w));
        }
        __syncthreads();   // vmcnt(0)+lgkmcnt(0): B-DMA and At ready
#pragma unroll
        for (int ks = 0; ks < 2; ++ks) {
            const int ch = ks * 4 + quad;
            int r = wm * 16 + lrow;
            bf16x8 afr = *(const bf16x8*)(At + r * 64 + ((ch ^ (r & 7)) << 3));
#pragma unroll
            for (int j = 0; j < 2; ++j) {
                int c = wn * 32 + j * 16 + lrow;
                bf16x8 bfr = *(const bf16x8*)(Btl + c * 64 + ((ch ^ (c & 7)) << 3));
                acc[j] = __builtin_amdgcn_mfma_f32_16x16x32_bf16(afr, bfr, acc[j], 0, 0, 0);
            }
        }
        __syncthreads();
    }
    u16* outp = (bN >> 3) ? Hf2 : Hf1b;
#pragma unroll
    for (int j = 0; j < 2; ++j) {
        int col = (bN & 7) * 64 + wn * 32 + j * 16 + lrow;
        float bb = (bN >> 3) ? 0.0f : b1[col];
#pragma unroll
        for (int r = 0; r < 4; r += 2) {
            int row = bM * 64 + wm * 16 + quad * 4 + r;
            u32 pk = pkbf(acc[j][r] + bb, acc[j][r + 1] + bb);
            outp[(size_t)row * DD + col] = (u16)pk;
            outp[(size_t)(row + 1) * DD + col] = (u16)(pk >> 16);
        }
    }
}

// ---------------------------------------------------------------------------
// Fused main — R8 frame unchanged structurally. This round: (a) A-stage math
// as float2 ext-vectors (lets the backend form v_pk_add/fma/max_f32; worst
// case identical scalar code), (b) epilogue bf16 conversion via packed
// v_cvt_pk_bf16_f32 on row-pairs + hi-extract (same RNE rounding).
// ---------------------------------------------------------------------------
__global__ __launch_bounds__(512) void fused_main(
    const u16* __restrict__ Hf1b, const u16* __restrict__ Hf2,
    const u16* __restrict__ W2T, const float* __restrict__ W1,
    const float* __restrict__ b2, const float* __restrict__ W3,
    const float* __restrict__ b3, const float* __restrict__ positions,
    float* __restrict__ out)
{
    const int b = blockIdx.x, n = blockIdx.y;     // b fastest -> XCD = b
    const int tid = threadIdx.x;
    const int base_bn = b * NTOK + n;
    const int wid = tid >> 6, lane = tid & 63, lrow = lane & 15, quad = lane >> 4;

    __shared__ __align__(16) u16 c0b[DD], c1b[DD], s1b[DD];  // bf16 coefs, 3 KB
    __shared__ __align__(16) u16 w3t[16 * 264];              // W3^T padded, 8.25 KB
    __shared__ __align__(16) char mbuf[49152];   // Atile 16K + Btile 32K | gh 34K
    u16* Atile = (u16*)mbuf;                     // [128][64] swizzled
    u16* Btile = (u16*)(mbuf + 16384);           // [256][64] swizzled
    u16* gh    = (u16*)mbuf;                     // [128][136] epilogue

    // ---- phase 0 ----
    {
        int k = tid;  // 512 threads == DD
        c0b[k] = f2bf(W1[(size_t)1024 * DD + k]);
        c1b[k] = f2bf(W1[(size_t)1025 * DD + k]);
        s1b[k] = Hf1b[(size_t)base_bn * DD + k];   // b1 already folded
    }
    {   // w3t: W3 (256x4 fp32) transposed, padded to 16 cols, bf16
        int c = tid & 15, kb2 = tid >> 4;          // kb2 0..31
        int k0w = kb2 * 8;
        u32 wv[4];
#pragma unroll
        for (int p = 0; p < 4; ++p) {
            int ka = k0w + p * 2;
            u16 va = (c < 4) ? f2bf(W3[ka * 4 + c])       : (u16)0;
            u16 vb = (c < 4) ? f2bf(W3[(ka + 1) * 4 + c]) : (u16)0;
            wv[p] = (u32)va | ((u32)vb << 16);
        }
        *(uint2*)(w3t + c * 264 + k0w)     = make_uint2(wv[0], wv[1]);
        *(uint2*)(w3t + c * 264 + k0w + 4) = make_uint2(wv[2], wv[3]);
    }
    const int mrow = tid >> 2, seg = tid & 3, swA = mrow & 7;
    float px, py;
    {
        float pnx = positions[(size_t)base_bn * 2 + 0];
        float pny = positions[(size_t)base_bn * 2 + 1];
        px = pnx - positions[(size_t)(b * NTOK + mrow) * 2 + 0];
        py = pny - positions[(size_t)(b * NTOK + mrow) * 2 + 1];
    }
    const f32x2 pxv = {px, px}, pyv = {py, py};
    // B-DMA lane source pointer (q-invariant swizzle, R8-proven)
    const int csrc = lane >> 3, wsrc = lane & 7;
    const u16* bsrc_lane = W2T + csrc * DD + ((wsrc ^ csrc) << 3);
    __syncthreads();

    const int wm = wid >> 2, wn = wid & 3;       // main GEMM 2x4 wave grid
    floatx4 acc[4][4];
#pragma unroll
    for (int i = 0; i < 4; ++i)
#pragma unroll
        for (int j = 0; j < 4; ++j) acc[i][j] = (floatx4)(0.0f);

    const u16* hf2p = Hf2 + (size_t)(b * NTOK + mrow) * DD;

    // ---- K loop ----
    for (int kc = 0; kc < 8; ++kc) {
        const int k0 = kc * 64;
        // stage B via LDS-DMA first (zero data regs; latency hidden by stage-A)
#pragma unroll
        for (int q = 0; q < 4; ++q) {
            const int slot = wid * 4 + q;        // wave-uniform
            __builtin_amdgcn_global_load_lds(
                (const __attribute__((address_space(1))) u32*)(bsrc_lane + slot * 8 * DD + k0),
                (__attribute__((address_space(3))) u32*)(Btile + slot * 512), 16, 0, 0);
        }

        const int kb = k0 + seg * 16;
        {   // stage A: h = relu(hf2 + s1 + px*c0 + py*c1), 16 elems/thread
            uint4 hv = *(const uint4*)(hf2p + kb);
            uint4 hw = *(const uint4*)(hf2p + kb + 8);
            uint4 sv = *(const uint4*)(s1b + kb);
            uint4 sw2 = *(const uint4*)(s1b + kb + 8);
            uint4 av = *(const uint4*)(c0b + kb);
            uint4 aw = *(const uint4*)(c0b + kb + 8);
            uint4 bv = *(const uint4*)(c1b + kb);
            uint4 bw = *(const uint4*)(c1b + kb + 8);
            auto hp = [&](u32 h, u32 s, u32 ca, u32 cb) -> u32 {
                f32x2 hh = {bflo(h),  bfhi(h)};
                f32x2 ss = {bflo(s),  bfhi(s)};
                f32x2 aa = {bflo(ca), bfhi(ca)};
                f32x2 bb = {bflo(cb), bfhi(cb)};
                f32x2 r = hh + ss;
                r += pxv * aa;
                r += pyv * bb;
                return pkbf(fmaxf(r.x, 0.0f), fmaxf(r.y, 0.0f));
            };
            uint4 o0 = make_uint4(hp(hv.x, sv.x, av.x, bv.x), hp(hv.y, sv.y, av.y, bv.y),
                                  hp(hv.z, sv.z, av.z, bv.z), hp(hv.w, sv.w, av.w, bv.w));
            uint4 o1 = make_uint4(hp(hw.x, sw2.x, aw.x, bw.x), hp(hw.y, sw2.y, aw.y, bw.y),
                                  hp(hw.z, sw2.z, aw.z, bw.z), hp(hw.w, sw2.w, aw.w, bw.w));
            *(uint4*)(Atile + mrow * 64 + (((seg * 2    ) ^ swA) << 3)) = o0;
            *(uint4*)(Atile + mrow * 64 + (((seg * 2 + 1) ^ swA) << 3)) = o1;
        }
        __syncthreads();   // vmcnt(0)+lgkmcnt(0) drain: Atile and B-DMA ready
#pragma unroll
        for (int ks = 0; ks < 2; ++ks) {
            const int ch = ks * 4 + quad;
            bf16x8 afr[4], bfr[4];
#pragma unroll
            for (int i = 0; i < 4; ++i) {
                int r = wm * 64 + i * 16 + lrow;
                afr[i] = *(const bf16x8*)(Atile + r * 64 + ((ch ^ (r & 7)) << 3));
            }
#pragma unroll
            for (int j = 0; j < 4; ++j) {
                int c = wn * 64 + j * 16 + lrow;
                bfr[j] = *(const bf16x8*)(Btile + c * 64 + ((ch ^ (c & 7)) << 3));
            }
#pragma unroll
            for (int i = 0; i < 4; ++i)
#pragma unroll
                for (int j = 0; j < 4; ++j)
                    acc[i][j] = __builtin_amdgcn_mfma_f32_16x16x32_bf16(afr[i], bfr[j], acc[i][j], 0, 0, 0);
        }
        __syncthreads();
    }

    // ---- epilogue: relu(acc+b2) -> gh bf16 halves -> layer-3 MFMA ----
    float b2v[4];
#pragma unroll
    for (int j = 0; j < 4; ++j) b2v[j] = b2[wn * 64 + j * 16 + lrow];

    const int smrow = wid * 16;                  // per-wave epilogue row block
    floatx4 acc3 = (floatx4)(0.0f);
#pragma unroll
    for (int half = 0; half < 2; ++half) {
        __syncthreads();
        if ((wn >> 1) == half) {
#pragma unroll
            for (int i = 0; i < 4; ++i)
#pragma unroll
                for (int j = 0; j < 4; ++j)
#pragma unroll
                    for (int r = 0; r < 4; r += 2) {
                        int row0 = wm * 64 + i * 16 + quad * 4 + r;
                        int col = (wn & 1) * 64 + j * 16 + lrow;
                        float v0 = fmaxf(acc[i][j][r]     + b2v[j], 0.0f);
                        float v1 = fmaxf(acc[i][j][r + 1] + b2v[j], 0.0f);
                        u32 pk = pkbf(v0, v1);
                        gh[row0 * 136 + col]       = (u16)pk;
                        gh[(row0 + 1) * 136 + col] = (u16)(pk >> 16);
                    }
        }
        __syncthreads();
#pragma unroll
        for (int ks = 0; ks < 4; ++ks) {
            bf16x8 gfrag = *(const bf16x8*)(gh + (smrow + lrow) * 136 + ks * 32 + quad * 8);
            bf16x8 wfrag = *(const bf16x8*)(w3t + lrow * 264 + half * 128 + ks * 32 + quad * 8);
            acc3 = __builtin_amdgcn_mfma_f32_16x16x32_bf16(gfrag, wfrag, acc3, 0, 0, 0);
        }
    }
    if (lrow < 4) {
        float bo = b3[lrow];
#pragma unroll
        for (int r = 0; r < 4; ++r) {
            int row = smrow + quad * 4 + r;
            out[(size_t)base_bn * 512 + row * 4 + lrow] = acc3[r] + bo;
        }
    }
}

// ---------------------------------------------------------------------------
extern "C" void kernel_launch(void* const* d_in, const int* in_sizes, int n_in,
                              void* d_out, int out_size, void* d_ws, size_t ws_size,
                              hipStream_t stream)
{
    const float* features  = (const float*)d_in[0];
    const float* positions = (const float*)d_in[1];
    const float* W1 = (const float*)d_in[2];
    const float* b1 = (const float*)d_in[3];
    const float* W2 = (const float*)d_in[4];
    const float* b2 = (const float*)d_in[5];
    const float* W3 = (const float*)d_in[6];
    const float* b3 = (const float*)d_in[7];
    float* out = (float*)d_out;

    char* ws = (char*)d_ws;
    u16* W2T  = (u16*)(ws);                 // 256*512*2  = 262144 B
    u16* Hf1b = (u16*)(ws + 262144);        // 1048576 B
    u16* Hf2  = (u16*)(ws + 1310720);       // 1048576 B
    u16* W1T  = (u16*)(ws + 2359296);       // 512*1024*2 = 1048576 B (total 3.25 MB)

    prep_t<<<dim3(160), 512, 0, stream>>>(W1, W2, W1T, W2T);
    prep_g<<<dim3(16, 16), 512, 0, stream>>>(features, W1T, b1, Hf1b, Hf2);
    fused_main<<<dim3(8, 128), 512, 0, stream>>>(Hf1b, Hf2, W2T, W1, b2, W3, b3,
                                                 positions, out);
}